// Round 18
// baseline (407.590 us; speedup 1.0000x reference)
//
#include <hip/hip_runtime.h>

typedef __attribute__((ext_vector_type(8))) short s16x8;
typedef __attribute__((ext_vector_type(4))) short s16x4;
typedef __attribute__((ext_vector_type(4))) float f32x4;

// ---------------- helpers ----------------

__device__ __forceinline__ unsigned short f2bf(float f) {
    union { float f; unsigned u; } v; v.f = f;
    unsigned r = v.u + 0x7FFFu + ((v.u >> 16) & 1u);   // RNE
    return (unsigned short)(r >> 16);
}

__device__ __forceinline__ float bf2f(unsigned short b) {
    union { unsigned u; float f; } v; v.u = ((unsigned)b) << 16;
    return v.f;
}

__device__ __forceinline__ unsigned cvt_pk_bf16(float lo, float hi) {
    unsigned r;
    asm("v_cvt_pk_bf16_f32 %0, %1, %2" : "=v"(r) : "v"(lo), "v"(hi));
    return r;
}

__device__ __forceinline__ float exp2_fast(float x) {
    float r;
    asm("v_exp_f32 %0, %1" : "=v"(r) : "v"(x));
    return r;
}

__device__ __forceinline__ float gelu_tanh(float x) {
    float u = 0.7978845608028654f * (x + 0.044715f * x * x * x);
    float au = fabsf(u);
    float t = 1.f - 2.f / (__expf(2.f * au) + 1.f);    // stable tanh(|u|)
    t = (u < 0.f) ? -t : t;
    return 0.5f * x * (1.f + t);
}

__device__ __forceinline__ void load_lds16(const void* g, void* l) {
    __builtin_amdgcn_global_load_lds(
        (const __attribute__((address_space(1))) void*)g,
        (__attribute__((address_space(3))) void*)l, 16, 0, 0);
}

// bijective XCD swizzle (gridDim.x*gridDim.y % 8 == 0 for all our grids)
__device__ __forceinline__ void xcd_remap(int& bx, int& by) {
    const int gx = gridDim.x;
    const int nwg = gx * gridDim.y;
    const int id = by * gx + bx;
    const int nid = (id & 7) * (nwg >> 3) + (id >> 3);
    bx = nid % gx; by = nid / gx;
}

// ---------------- fused pre-pass: convert + all weight transposes ------------
// blocks [0,4096): x f32 -> bf16.  [4096,7168): Wq/Wk/Wv transpose.
// [7168,8192): Wo. [8192,12288): W1. [12288,16384): W2. All independent.
__global__ __launch_bounds__(256) void prep_k(
    const float* __restrict__ x,  const float* __restrict__ Wq,
    const float* __restrict__ Wk, const float* __restrict__ Wv,
    const float* __restrict__ Wo, const float* __restrict__ W1,
    const float* __restrict__ W2,
    unsigned short* __restrict__ x_bf, unsigned short* __restrict__ WqkT,
    unsigned short* __restrict__ WvT,  unsigned short* __restrict__ WoT,
    unsigned short* __restrict__ W1T,  unsigned short* __restrict__ W2T)
{
    __shared__ float tile[32][33];
    const int blk = blockIdx.x;
    const int tid = threadIdx.x;
    if (blk < 4096) {                       // convert x -> bf16
        const int i = blk * 1024 + tid * 4;
        float4 v = *(const float4*)(x + i);
        ushort4 o;
        o.x = f2bf(v.x); o.y = f2bf(v.y); o.z = f2bf(v.z); o.w = f2bf(v.w);
        *(ushort4*)(x_bf + i) = o;
        return;
    }
    const int tx = tid & 31, ty = tid >> 5;     // 32 x 8
    const float* in; unsigned short* out; int R, C, b, bx, by;
    if (blk < 7168) {                       // qkv transposes (3072 blocks)
        int lb = blk - 4096;
        bx = lb & 1; lb >>= 1;
        by = lb & 31;
        const int z = lb >> 5;              // 0..47
        const int which = z >> 4; b = z & 15;
        in  = (which == 0) ? Wq : (which == 1) ? Wk : Wv;
        out = (which == 0) ? WqkT : (which == 1) ? (WqkT + 1024*1024) : WvT;
        R = 1024; C = 64;
    } else if (blk < 8192) {                // Wo (1024 blocks, grid 32x32)
        const int lb = blk - 7168;
        bx = lb & 31; by = lb >> 5;
        in = Wo; out = WoT; R = 1024; C = 1024; b = 0;
    } else if (blk < 12288) {               // W1 (4096 blocks, grid 128x32)
        const int lb = blk - 8192;
        bx = lb & 127; by = lb >> 7;
        in = W1; out = W1T; R = 1024; C = 4096; b = 0;
    } else {                                // W2 (4096 blocks, grid 32x128)
        const int lb = blk - 12288;
        bx = lb & 31; by = lb >> 5;
        in = W2; out = W2T; R = 4096; C = 1024; b = 0;
    }
    const int c0 = bx * 32, r0 = by * 32;
    const float* inb = in + (size_t)b * R * C;
    unsigned short* outb = out + (size_t)b * R * C;
    #pragma unroll
    for (int i = 0; i < 4; ++i)
        tile[ty + i*8][tx] = inb[(size_t)(r0 + ty + i*8) * C + c0 + tx];
    __syncthreads();
    #pragma unroll
    for (int i = 0; i < 4; ++i)
        outb[(size_t)(c0 + ty + i*8) * R + r0 + tx] = f2bf(tile[tx][ty + i*8]);
}

// ---------------- GEMM 128x128 tile, 3-buf depth-2, 1 barrier/step -----------
// EPI 0: Cb = bf16(AB)
// EPI 4: Cb = bf16(AB * (col<1024 ? 0.125*log2e : 1))   (QK, Q in exp2 domain)
// EPI 5: split-K partial: Cb[z] = bf16(AB over K-chunk z) (MLP2; grid.z = 2)
template<int EPI>
__global__ __launch_bounds__(256) void gemm_bt(
    const unsigned short* __restrict__ A,
    const unsigned short* __restrict__ BT,
    const float* __restrict__ bias,
    const float* __restrict__ resid,
    float* __restrict__ Cf,
    unsigned short* __restrict__ Cb,
    int M, int N, int K, int klen)
{
    __shared__ unsigned short As[3][128 * 32];
    __shared__ unsigned short Bs[3][128 * 32];
    const int tid = threadIdx.x;
    const int w  = tid >> 6, l = tid & 63;
    const int wr = w >> 1,  wc = w & 1;
    const int lg = l >> 4,  ll = l & 15;
    int bx = blockIdx.x, by = blockIdx.y;
    xcd_remap(bx, by);
    const int m0 = by * 128, n0 = bx * 128;
    const int koff = (EPI == 5) ? (int)blockIdx.z * klen : 0;

    const int srow = w * 16 + (l >> 2);                     // staging row (i adds 64)
    const int scol = (((l & 3) ^ ((l >> 2) & 3))) * 8;      // swizzled source granule

    f32x4 acc[4][4] = {};

    auto stage = [&](int buf, int k0) {
        #pragma unroll
        for (int i = 0; i < 2; ++i) {
            load_lds16(A  + (size_t)(m0 + srow + i*64) * K + koff + k0 + scol,
                       (char*)As[buf] + i*4096 + w*1024);
            load_lds16(BT + (size_t)(n0 + srow + i*64) * K + koff + k0 + scol,
                       (char*)Bs[buf] + i*4096 + w*1024);
        }
    };

    const int nsteps = ((EPI == 5) ? klen : K) >> 5;
    stage(0, 0); stage(1, 32);
    int buf = 0;
    for (int s = 0; s < nsteps; ++s) {
        if (s + 1 < nsteps) asm volatile("s_waitcnt vmcnt(4)" ::: "memory");
        else                asm volatile("s_waitcnt vmcnt(0)" ::: "memory");
        __builtin_amdgcn_s_barrier();
        s16x8 a[4], b[4];
        #pragma unroll
        for (int m = 0; m < 4; ++m) {
            const int row = wr*64 + m*16 + ll;
            a[m] = *(const s16x8*)&As[buf][row * 32 + ((lg ^ (ll & 3)) * 8)];
        }
        #pragma unroll
        for (int n = 0; n < 4; ++n) {
            const int row = wc*64 + n*16 + ll;
            b[n] = *(const s16x8*)&Bs[buf][row * 32 + ((lg ^ (ll & 3)) * 8)];
        }
        int bnext = buf + 2; if (bnext >= 3) bnext -= 3;
        if (s + 2 < nsteps) stage(bnext, (s + 2) << 5);
        __builtin_amdgcn_s_setprio(1);
        #pragma unroll
        for (int m = 0; m < 4; ++m)
            #pragma unroll
            for (int n = 0; n < 4; ++n)
                acc[m][n] = __builtin_amdgcn_mfma_f32_16x16x32_bf16(a[m], b[n], acc[m][n], 0, 0, 0);
        __builtin_amdgcn_s_setprio(0);
        buf = (buf == 2) ? 0 : buf + 1;
    }

    unsigned short* Cbz = (EPI == 5) ? (Cb + (size_t)blockIdx.z * M * N) : Cb;
    #pragma unroll
    for (int m = 0; m < 4; ++m) {
        #pragma unroll
        for (int n = 0; n < 4; ++n) {
            const int col = n0 + wc*64 + n*16 + ll;
            #pragma unroll
            for (int r = 0; r < 4; ++r) {
                const int row = m0 + wr*64 + m*16 + lg*4 + r;
                float v = acc[m][n][r];
                if constexpr (EPI == 4) v *= (col < 1024) ? 0.1803368801f : 1.0f;
                Cbz[(size_t)row * N + col] = f2bf(v);
            }
        }
    }
}

// ---------------- MLP1: 256x256 tile, 8 waves, 3-buf/1-barrier ---------------
// (r16-verified version)
__global__ __launch_bounds__(512) void gemm_mlp1_k(
    const unsigned short* __restrict__ A,
    const unsigned short* __restrict__ BT,
    const float* __restrict__ bias,
    unsigned short* __restrict__ Cb,
    int M, int N, int K)
{
    __shared__ unsigned short As[3][256 * 32];
    __shared__ unsigned short Bs[3][256 * 32];
    const int tid = threadIdx.x;
    const int w  = tid >> 6, l = tid & 63;      // w in [0,8)
    const int wr = w >> 2,  wc = w & 3;         // 2 x 4 wave grid
    const int lg = l >> 4,  ll = l & 15;
    int bx = blockIdx.x, by = blockIdx.y;
    xcd_remap(bx, by);
    const int m0 = by * 256, n0 = bx * 256;

    const int srow = w * 16 + (l >> 2);         // +i*128 for second half
    const int scol = (((l & 3) ^ ((l >> 2) & 3))) * 8;

    f32x4 acc[8][4] = {};

    auto stage = [&](int buf, int k0) {
        #pragma unroll
        for (int i = 0; i < 2; ++i) {
            load_lds16(A  + (size_t)(m0 + srow + i*128) * K + k0 + scol,
                       (char*)As[buf] + i*8192 + w*1024);
            load_lds16(BT + (size_t)(n0 + srow + i*128) * K + k0 + scol,
                       (char*)Bs[buf] + i*8192 + w*1024);
        }
    };

    const int nsteps = K >> 5;
    stage(0, 0); stage(1, 32);
    int buf = 0;
    for (int s = 0; s < nsteps; ++s) {
        if (s + 1 < nsteps) asm volatile("s_waitcnt vmcnt(4)" ::: "memory");
        else                asm volatile("s_waitcnt vmcnt(0)" ::: "memory");
        __builtin_amdgcn_s_barrier();
        s16x8 a[8], b[4];
        #pragma unroll
        for (int m = 0; m < 8; ++m) {
            const int row = wr*128 + m*16 + ll;         // 0..255
            a[m] = *(const s16x8*)&As[buf][row * 32 + ((lg ^ (ll & 3)) * 8)];
        }
        #pragma unroll
        for (int n = 0; n < 4; ++n) {
            const int row = wc*64 + n*16 + ll;          // 0..255
            b[n] = *(const s16x8*)&Bs[buf][row * 32 + ((lg ^ (ll & 3)) * 8)];
        }
        int bnext = buf + 2; if (bnext >= 3) bnext -= 3;
        if (s + 2 < nsteps) stage(bnext, (s + 2) << 5);
        __builtin_amdgcn_s_setprio(1);
        #pragma unroll
        for (int m = 0; m < 8; ++m)
            #pragma unroll
            for (int n = 0; n < 4; ++n)
                acc[m][n] = __builtin_amdgcn_mfma_f32_16x16x32_bf16(a[m], b[n], acc[m][n], 0, 0, 0);
        __builtin_amdgcn_s_setprio(0);
        buf = (buf == 2) ? 0 : buf + 1;
    }

    #pragma unroll
    for (int m = 0; m < 8; ++m) {
        #pragma unroll
        for (int n = 0; n < 4; ++n) {
            const int col = n0 + wc*64 + n*16 + ll;
            #pragma unroll
            for (int r = 0; r < 4; ++r) {
                const int row = m0 + wr*128 + m*16 + lg*4 + r;
                Cb[(size_t)row * N + col] = f2bf(gelu_tanh(acc[m][n][r] + bias[col]));
            }
        }
    }
}

// ---------------- GEMM 128x64 tile, depth-4 pipeline --------------------------
// EPI 0: Cb = bf16(AB)                        (Vt)
// EPI 1: v = AB+bias+resid; Cf=v; Cb=bf16(v)  (Wo)
template<int EPI>
__global__ __launch_bounds__(256) void gemm_bt64(
    const unsigned short* __restrict__ A,
    const unsigned short* __restrict__ BT,
    const float* __restrict__ bias,
    const float* __restrict__ resid,
    float* __restrict__ Cf,
    unsigned short* __restrict__ Cb,
    int M, int N, int K)
{
    __shared__ unsigned short As[4][128 * 32];
    __shared__ unsigned short Bs[4][64 * 32];
    const int tid = threadIdx.x;
    const int w  = tid >> 6, l = tid & 63;
    const int lg = l >> 4,  ll = l & 15;
    int bx = blockIdx.x, by = blockIdx.y;
    xcd_remap(bx, by);
    const int m0 = by * 128, n0 = bx * 64;

    const int srowA = w * 16 + (l >> 2);
    const int scolA = (((l & 3) ^ ((l >> 2) & 3))) * 8;
    const int srowB = tid >> 2;
    const int scolB = (((tid & 3) ^ ((tid >> 2) & 3))) * 8;

    f32x4 acc[2][4] = {};

    auto stage = [&](int buf, int k0) {
        #pragma unroll
        for (int i = 0; i < 2; ++i)
            load_lds16(A + (size_t)(m0 + srowA + i*64) * K + k0 + scolA,
                       (char*)As[buf] + i*4096 + w*1024);
        load_lds16(BT + (size_t)(n0 + srowB) * K + k0 + scolB,
                   (char*)Bs[buf] + w*1024);
    };

    const int nsteps = K >> 5;                 // >= 32 for all our K
    stage(0, 0); stage(1, 32); stage(2, 64);
    int buf = 0;
    for (int s = 0; s < nsteps; ++s) {
        const int rem = nsteps - 1 - s;
        if (rem >= 2)      asm volatile("s_waitcnt vmcnt(6)" ::: "memory");
        else if (rem == 1) asm volatile("s_waitcnt vmcnt(3)" ::: "memory");
        else               asm volatile("s_waitcnt vmcnt(0)" ::: "memory");
        __builtin_amdgcn_s_barrier();
        s16x8 a[2], b[4];
        #pragma unroll
        for (int m = 0; m < 2; ++m) {
            const int row = w*32 + m*16 + ll;
            a[m] = *(const s16x8*)&As[buf][row * 32 + ((lg ^ (ll & 3)) * 8)];
        }
        #pragma unroll
        for (int n = 0; n < 4; ++n) {
            const int row = n*16 + ll;
            b[n] = *(const s16x8*)&Bs[buf][row * 32 + ((lg ^ (ll & 3)) * 8)];
        }
        int bnext = buf + 3; if (bnext >= 4) bnext -= 4;
        if (s + 3 < nsteps) stage(bnext, (s + 3) << 5);
        __builtin_amdgcn_s_setprio(1);
        #pragma unroll
        for (int m = 0; m < 2; ++m)
            #pragma unroll
            for (int n = 0; n < 4; ++n)
                acc[m][n] = __builtin_amdgcn_mfma_f32_16x16x32_bf16(a[m], b[n], acc[m][n], 0, 0, 0);
        __builtin_amdgcn_s_setprio(0);
        buf = (buf + 1) & 3;
    }

    #pragma unroll
    for (int m = 0; m < 2; ++m) {
        #pragma unroll
        for (int n = 0; n < 4; ++n) {
            const int col = n0 + n*16 + ll;
            #pragma unroll
            for (int r = 0; r < 4; ++r) {
                const int row = m0 + w*32 + m*16 + lg*4 + r;
                float v = acc[m][n][r];
                if constexpr (EPI == 1) v += bias[col] + resid[(size_t)row * N + col];
                Cb[(size_t)row * N + col] = f2bf(v);
                if constexpr (EPI == 1)
                    Cf[(size_t)row * N + col] = v;
            }
        }
    }
}

// MLP2 combine: out = p0 + p1 + bias + resid   (f32 final output)
__global__ __launch_bounds__(256) void mlp2_combine_k(
    const unsigned short* __restrict__ P,   // [2][4096][1024] bf16 partials
    const float* __restrict__ bias,
    const float* __restrict__ resid,
    float* __restrict__ out)
{
    const int idx = (blockIdx.x * 256 + threadIdx.x) * 4;
    const int col = idx & 1023;
    ushort4 a = *(const ushort4*)(P + idx);
    ushort4 b = *(const ushort4*)(P + 4194304 + idx);
    float4 rs = *(const float4*)(resid + idx);
    float4 o;
    o.x = bf2f(a.x) + bf2f(b.x) + bias[col]     + rs.x;
    o.y = bf2f(a.y) + bf2f(b.y) + bias[col + 1] + rs.y;
    o.z = bf2f(a.z) + bf2f(b.z) + bias[col + 2] + rs.z;
    o.w = bf2f(a.w) + bf2f(b.w) + bias[col + 3] + rs.w;
    *(float4*)(out + idx) = o;
}

// ---------------- flash attention: pair-pipelined tiles, padded LDS -----------
// r17 structure (LDK=72 padded LDS, reg-staged K/V, one barrier per pair) with
// the tile PAIR software-pipelined: QK(t) -> softmax(t) -> QK(t+1) -> PV(t)
// -> softmax(t+1) -> PV(t+1). A wave's MFMA issue doesn't block VALU issue,
// so QK(t+1) and PV(t) keep the matrix pipe busy under every softmax stretch
// (attn floor is ~20us of pure MFMA; we run 52us at MfmaUtil 30% -> issue-
// order stalls are the gap). Same math, same barriers. launch_bounds(512,4)
// pins VGPR <= 128 so 2 WGs/CU (16 waves) residency is preserved.
__global__ __launch_bounds__(512, 4) void attn_k(
    const unsigned short* __restrict__ Rq,  // K_mat rows (output rows), stride 2048
    const unsigned short* __restrict__ Ck,  // Q_mat (staged tiles, exp2-prescaled)
    const unsigned short* __restrict__ Vt,  // V^T [1024][4096]
    unsigned short* __restrict__ Ppart,     // [2][4096][1024] bf16 partial o
    float* __restrict__ Lpart)              // [2][4096][16]  f32 partial lsum
{
    constexpr int LDK = 72;                 // padded row, 144B
    __shared__ unsigned short Ks[2][2][64 * LDK];
    __shared__ unsigned short Vs[2][2][64 * LDK];

    const int bx = blockIdx.x;
    const int h  = bx & 15;
    const int j  = (bx >> 4) & 1;           // kv half
    const int sb = 15 - (bx >> 5);          // 256-row s-blocks, heavy first
    const int half = 2*sb + 2;
    const int t0 = j ? half : 0;
    const int npairs = sb + 1;              // tiles per half / 2

    const int tid = threadIdx.x;
    const int w = tid >> 6, l = tid & 63;   // w in [0,8)
    const int lg = l >> 4, ll = l & 15;

    // staging: each wave stages rows w*8..w*8+7 of K tile and of V^T tile
    const int srow = w*8 + (l >> 3);
    const int sgE  = (l & 7) * 8;           // element offset within row
    const size_t kGb = (size_t)srow * 2048 + h*64 + sgE;
    const size_t vGb = (size_t)(h*64 + srow) * 4096 + sgE;
    const int ldsW = srow * LDK + sgE;      // element offset (16B-aligned)

    // QK LDS read byte-offsets (plain layout, padded stride)
    int qkoff[4][2];
    #pragma unroll
    for (int jj = 0; jj < 4; ++jj) {
        const int row = jj*16 + ll;
        qkoff[jj][0] = row*144 + lg*16;
        qkoff[jj][1] = row*144 + (4 + lg)*16;
    }
    // PV LDS read byte-offsets
    int pvoff[4][2][2];
    #pragma unroll
    for (int n = 0; n < 4; ++n) {
        const int row = n*16 + ll;
        #pragma unroll
        for (int c = 0; c < 2; ++c) {
            const int gl = c*4     + (lg >> 1);
            const int gh = c*4 + 2 + (lg >> 1);
            pvoff[n][c][0] = row*144 + gl*16 + (lg & 1)*8;
            pvoff[n][c][1] = row*144 + gh*16 + (lg & 1)*8;
        }
    }

    s16x8 kr[2], vr[2];                     // staged pair (K,V x 2 tiles)
    auto loadPair = [&](int p) {
        const int t = t0 + 2*p;
        kr[0] = *(const s16x8*)&Ck[(size_t)t * 131072 + kGb];
        vr[0] = *(const s16x8*)&Vt[(size_t)t * 64 + vGb];
        kr[1] = *(const s16x8*)&Ck[(size_t)(t + 1) * 131072 + kGb];
        vr[1] = *(const s16x8*)&Vt[(size_t)(t + 1) * 64 + vGb];
    };
    auto writePair = [&](int set) {
        *(s16x8*)&Ks[set][0][ldsW] = kr[0];
        *(s16x8*)&Vs[set][0][ldsW] = vr[0];
        *(s16x8*)&Ks[set][1][ldsW] = kr[1];
        *(s16x8*)&Vs[set][1][ldsW] = vr[1];
    };

    // two rowsets of 16 output rows each (32 rows per wave)
    const int row0 = sb*256 + w*32;
    const int qgA  = row0 + ll;             // rowset 0: lane's output row
    const int qgB  = row0 + 16 + ll;        // rowset 1
    const size_t rbA = (size_t)qgA * 2048 + h*64;
    const size_t rbB = (size_t)qgB * 2048 + h*64;
    const s16x8 rA0 = *(const s16x8*)&Rq[rbA + lg*8];
    const s16x8 rA1 = *(const s16x8*)&Rq[rbA + 32 + lg*8];
    const s16x8 rB0 = *(const s16x8*)&Rq[rbB + lg*8];
    const s16x8 rB1 = *(const s16x8*)&Rq[rbB + 32 + lg*8];

    const short onebf = (short)0x3F80;      // bf16 1.0
    const s16x8 ones = {onebf, onebf, onebf, onebf, onebf, onebf, onebf, onebf};

    f32x4 o[2][4] = {};
    f32x4 o4[2] = {};                       // rowsum(P) accumulators

    // QK^T for one tile into st[2][4]
    auto qk = [&](const char* kb, f32x4 st[2][4]) {
        __builtin_amdgcn_s_setprio(1);
        #pragma unroll
        for (int jj = 0; jj < 4; ++jj) {
            s16x8 k0 = *(const s16x8*)(kb + qkoff[jj][0]);
            s16x8 k1 = *(const s16x8*)(kb + qkoff[jj][1]);
            f32x4 z = {0.f, 0.f, 0.f, 0.f};
            f32x4 ta = __builtin_amdgcn_mfma_f32_16x16x32_bf16(k0, rA0, z, 0, 0, 0);
            st[0][jj] = __builtin_amdgcn_mfma_f32_16x16x32_bf16(k1, rA1, ta, 0, 0, 0);
            f32x4 tb = __builtin_amdgcn_mfma_f32_16x16x32_bf16(k0, rB0, z, 0, 0, 0);
            st[1][jj] = __builtin_amdgcn_mfma_f32_16x16x32_bf16(k1, rB1, tb, 0, 0, 0);
        }
        __builtin_amdgcn_s_setprio(0);
    };
    // softmax + bf16-pack for one tile
    auto smpack = [&](int t, const f32x4 st[2][4], s16x8 apv[2][2]) {
        const bool anyMask = (t*64 + 63 > row0);
        float p[2][4][4];
        if (anyMask) {
            #pragma unroll
            for (int jj = 0; jj < 4; ++jj)
                #pragma unroll
                for (int r = 0; r < 4; ++r) {
                    const int jg = t*64 + jj*16 + lg*4 + r;
                    p[0][jj][r] = exp2_fast((jg > qgA) ? -3e38f : st[0][jj][r]);
                    p[1][jj][r] = exp2_fast((jg > qgB) ? -3e38f : st[1][jj][r]);
                }
        } else {
            #pragma unroll
            for (int rs = 0; rs < 2; ++rs)
                #pragma unroll
                for (int jj = 0; jj < 4; ++jj)
                    #pragma unroll
                    for (int r = 0; r < 4; ++r)
                        p[rs][jj][r] = exp2_fast(st[rs][jj][r]);
        }
        #pragma unroll
        for (int rs = 0; rs < 2; ++rs)
            #pragma unroll
            for (int c = 0; c < 2; ++c) {
                union { unsigned u[4]; s16x8 v; } pk;
                pk.u[0] = cvt_pk_bf16(p[rs][2*c][0],   p[rs][2*c][1]);
                pk.u[1] = cvt_pk_bf16(p[rs][2*c][2],   p[rs][2*c][3]);
                pk.u[2] = cvt_pk_bf16(p[rs][2*c+1][0], p[rs][2*c+1][1]);
                pk.u[3] = cvt_pk_bf16(p[rs][2*c+1][2], p[rs][2*c+1][3]);
                apv[rs][c] = pk.v;
            }
    };
    // lsum + PV MFMA for one tile
    auto pv = [&](const char* vb, const s16x8 apv[2][2]) {
        __builtin_amdgcn_s_setprio(1);
        #pragma unroll
        for (int rs = 0; rs < 2; ++rs) {
            o4[rs] = __builtin_amdgcn_mfma_f32_16x16x32_bf16(apv[rs][0], ones, o4[rs], 0, 0, 0);
            o4[rs] = __builtin_amdgcn_mfma_f32_16x16x32_bf16(apv[rs][1], ones, o4[rs], 0, 0, 0);
        }
        #pragma unroll
        for (int n = 0; n < 4; ++n) {
            #pragma unroll
            for (int c = 0; c < 2; ++c) {
                s16x4 lo = *(const s16x4*)(vb + pvoff[n][c][0]);
                s16x4 hi = *(const s16x4*)(vb + pvoff[n][c][1]);
                union { s16x4 h2[2]; s16x8 v; } u;
                u.h2[0] = lo; u.h2[1] = hi;
                o[0][n] = __builtin_amdgcn_mfma_f32_16x16x32_bf16(apv[0][c], u.v, o[0][n], 0, 0, 0);
                o[1][n] = __builtin_amdgcn_mfma_f32_16x16x32_bf16(apv[1][c], u.v, o[1][n], 0, 0, 0);
            }
        }
        __builtin_amdgcn_s_setprio(0);
    };

    loadPair(0);
    for (int p = 0; p < npairs; ++p) {
        const int set = p & 1;
        writePair(set);                     // compiler inserts vmcnt waits on kr/vr
        __syncthreads();                    // lgkm drain + barrier
        if (p + 1 < npairs) loadPair(p + 1);
        const int t = t0 + 2*p;
        const char* kb0 = (const char*)Ks[set][0];
        const char* vb0 = (const char*)Vs[set][0];
        const char* kb1 = (const char*)Ks[set][1];
        const char* vb1 = (const char*)Vs[set][1];
        const bool liveA = (t*64 <= row0 + 31);
        const bool liveB = ((t+1)*64 <= row0 + 31);
        if (!liveA) continue;               // liveB implies liveA (monotone)

        // pair pipeline: QK(t), sm(t), QK(t+1), PV(t), sm(t+1), PV(t+1)
        f32x4 st0[2][4], st1[2][4];
        s16x8 apv0[2][2], apv1[2][2];
        qk(kb0, st0);
        smpack(t, st0, apv0);
        if (liveB) qk(kb1, st1);
        pv(vb0, apv0);
        if (liveB) {
            smpack(t + 1, st1, apv1);
            pv(vb1, apv1);
        }
    }

    // epilogue: write UNNORMALIZED partials (additive across halves)
    unsigned short* Pout = Ppart + (size_t)j * 4194304;     // 4096*1024
    float* Lout = Lpart + (size_t)j * 65536;                // 4096*16
    #pragma unroll
    for (int rs = 0; rs < 2; ++rs)
        #pragma unroll
        for (int r = 0; r < 4; ++r) {
            const int row = row0 + rs*16 + lg*4 + r;
            const size_t orow = (size_t)row * 1024 + h * 64;
            #pragma unroll
            for (int n = 0; n < 4; ++n)
                Pout[orow + n*16 + ll] = f2bf(o[rs][n][r]);
            if (ll == 0) Lout[row * 16 + h] = o4[rs][r];
        }
}

// combine: attn[row][col] = (P0 + P1) / (L0 + L1)
__global__ __launch_bounds__(256) void attn_combine_k(
    const unsigned short* __restrict__ P,   // [2][4096][1024] bf16
    const float* __restrict__ L,            // [2][4096][16]  f32
    unsigned short* __restrict__ Out)       // [4096][1024]   bf16
{
    const int idx = (blockIdx.x * 256 + threadIdx.x) * 4;
    const int row = idx >> 10, h = (idx & 1023) >> 6;
    const float inv = 1.f / (L[row*16 + h] + L[65536 + row*16 + h]);
    ushort4 a = *(const ushort4*)(P + idx);
    ushort4 b = *(const ushort4*)(P + 4194304 + idx);
    ushort4 o;
    o.x = f2bf((bf2f(a.x) + bf2f(b.x)) * inv);
    o.y = f2bf((bf2f(a.y) + bf2f(b.y)) * inv);
    o.z = f2bf((bf2f(a.z) + bf2f(b.z)) * inv);
    o.w = f2bf((bf2f(a.w) + bf2f(b.w)) * inv);
    *(ushort4*)(Out + idx) = o;
}

// ---------------- launch ----------------

extern "C" void kernel_launch(void* const* d_in, const int* in_sizes, int n_in,
                              void* d_out, int out_size, void* d_ws, size_t ws_size,
                              hipStream_t stream) {
    const float* x  = (const float*)d_in[0];
    const float* Wk = (const float*)d_in[1];
    const float* Wq = (const float*)d_in[2];
    const float* Wv = (const float*)d_in[3];
    const float* Wo = (const float*)d_in[4];
    const float* bo = (const float*)d_in[5];
    const float* W1 = (const float*)d_in[6];
    const float* b1 = (const float*)d_in[7];
    const float* W2 = (const float*)d_in[8];
    const float* b2 = (const float*)d_in[9];
    float* out = (float*)d_out;

    char* ws = (char*)d_ws;
    unsigned short* x_bf  = (unsigned short*)(ws);                // 0..8 MiB
    unsigned short* WqkT  = (unsigned short*)(ws + (8u  << 20));  // 8..12 (2048x1024)
    unsigned short* WvT   = (unsigned short*)(ws + (12u << 20));  // 12..14 (1024x1024)
    unsigned short* WoT   = (unsigned short*)(ws + (14u << 20));  // 14..16
    unsigned short* W1T   = (unsigned short*)(ws + (16u << 20));  // 16..24
    unsigned short* W2T   = (unsigned short*)(ws + (24u << 20));  // 24..32
    unsigned short* QKm   = (unsigned short*)(ws + (32u << 20));  // 32..48 (4096x2048)
    unsigned short* attn  = (unsigned short*)(ws + (48u << 20));  // 48..56
    unsigned short* Vt    = (unsigned short*)(ws + (56u << 20));  // 56..64 (1024x4096)
    float*          yf    = (float*)(ws + (64u << 20));           // 64..80 f32
    // dead-region reuse:
    float*          Lpart = (float*)ws;                           // attn lsum partials (x_bf region)
    unsigned short* Ppart = (unsigned short*)(ws + (64u << 20));  // attn o partials (yf region)
    unsigned short* Pmlp  = (unsigned short*)(ws);                // MLP2 partials, 0..16 MiB (dead by then)
    unsigned short* y_bf  = x_bf;                                 // x_bf dead after V-GEMM
    unsigned short* h_bf  = QKm;   // 32..64 MiB (QKm+attn+Vt dead after Wo GEMM)

    // fused pre-pass: convert + all transposes in ONE dispatch
    prep_k<<<16384, 256, 0, stream>>>(x, Wq, Wk, Wv, Wo, W1, W2,
                                      x_bf, WqkT, WvT, WoT, W1T, W2T);

    // fused Q|K projection (128^2 tiles), Q pre-scaled by 0.125*log2e (exp2 domain)
    gemm_bt<4><<<dim3(16, 32), 256, 0, stream>>>(x_bf, WqkT, nullptr, nullptr, nullptr,
                                                 QKm, 4096, 2048, 1024, 1024);
    // V^T directly: Vt[e][s] = sum_d WvT[e][d] * x[s][d]
    gemm_bt64<0><<<dim3(64, 8), 256, 0, stream>>>(WvT, x_bf, nullptr, nullptr, nullptr,
                                                  Vt, 1024, 4096, 1024);

    attn_k<<<512, 512, 0, stream>>>(QKm + 1024 /*K*/, QKm /*Q*/, Vt, Ppart, Lpart);
    attn_combine_k<<<4096, 256, 0, stream>>>(Ppart, Lpart, attn);

    gemm_bt64<1><<<dim3(16, 32), 256, 0, stream>>>(attn, WoT, bo, x, yf, y_bf,
                                                   4096, 1024, 1024);
    // MLP1: 256x256 tile, 8 waves, 3-buf -> 256 WGs = exactly 1/CU
    gemm_mlp1_k<<<dim3(16, 16), 512, 0, stream>>>(y_bf, W1T, b1, h_bf, 4096, 4096, 1024);
    // MLP2: 128^2 tile + split-K x2 (grid.z = 2, K=2048 each), bf16 partials + combine
    gemm_bt<5><<<dim3(8, 32, 2), 256, 0, stream>>>(h_bf, W2T, nullptr, nullptr, nullptr,
                                                   Pmlp, 4096, 1024, 4096, 2048);
    mlp2_combine_k<<<4096, 256, 0, stream>>>(Pmlp, b2, yf, out);
}

// Round 19
// 224.668 us; speedup vs baseline: 1.8142x; 1.8142x over previous
//
#include <hip/hip_runtime.h>

typedef __attribute__((ext_vector_type(8))) short s16x8;
typedef __attribute__((ext_vector_type(4))) short s16x4;
typedef __attribute__((ext_vector_type(4))) float f32x4;

// ---------------- helpers ----------------

__device__ __forceinline__ unsigned short f2bf(float f) {
    union { float f; unsigned u; } v; v.f = f;
    unsigned r = v.u + 0x7FFFu + ((v.u >> 16) & 1u);   // RNE
    return (unsigned short)(r >> 16);
}

__device__ __forceinline__ float bf2f(unsigned short b) {
    union { unsigned u; float f; } v; v.u = ((unsigned)b) << 16;
    return v.f;
}

__device__ __forceinline__ unsigned cvt_pk_bf16(float lo, float hi) {
    unsigned r;
    asm("v_cvt_pk_bf16_f32 %0, %1, %2" : "=v"(r) : "v"(lo), "v"(hi));
    return r;
}

__device__ __forceinline__ float exp2_fast(float x) {
    float r;
    asm("v_exp_f32 %0, %1" : "=v"(r) : "v"(x));
    return r;
}

__device__ __forceinline__ float gelu_tanh(float x) {
    float u = 0.7978845608028654f * (x + 0.044715f * x * x * x);
    float au = fabsf(u);
    float t = 1.f - 2.f / (__expf(2.f * au) + 1.f);    // stable tanh(|u|)
    t = (u < 0.f) ? -t : t;
    return 0.5f * x * (1.f + t);
}

__device__ __forceinline__ void load_lds16(const void* g, void* l) {
    __builtin_amdgcn_global_load_lds(
        (const __attribute__((address_space(1))) void*)g,
        (__attribute__((address_space(3))) void*)l, 16, 0, 0);
}

// bijective XCD swizzle (gridDim.x*gridDim.y % 8 == 0 for all our grids)
__device__ __forceinline__ void xcd_remap(int& bx, int& by) {
    const int gx = gridDim.x;
    const int nwg = gx * gridDim.y;
    const int id = by * gx + bx;
    const int nid = (id & 7) * (nwg >> 3) + (id >> 3);
    bx = nid % gx; by = nid / gx;
}

// ---------------- fused pre-pass: convert + all weight transposes ------------
// blocks [0,4096): x f32 -> bf16.  [4096,7168): Wq/Wk/Wv transpose.
// [7168,8192): Wo. [8192,12288): W1. [12288,16384): W2. All independent.
__global__ __launch_bounds__(256) void prep_k(
    const float* __restrict__ x,  const float* __restrict__ Wq,
    const float* __restrict__ Wk, const float* __restrict__ Wv,
    const float* __restrict__ Wo, const float* __restrict__ W1,
    const float* __restrict__ W2,
    unsigned short* __restrict__ x_bf, unsigned short* __restrict__ WqkT,
    unsigned short* __restrict__ WvT,  unsigned short* __restrict__ WoT,
    unsigned short* __restrict__ W1T,  unsigned short* __restrict__ W2T)
{
    __shared__ float tile[32][33];
    const int blk = blockIdx.x;
    const int tid = threadIdx.x;
    if (blk < 4096) {                       // convert x -> bf16
        const int i = blk * 1024 + tid * 4;
        float4 v = *(const float4*)(x + i);
        ushort4 o;
        o.x = f2bf(v.x); o.y = f2bf(v.y); o.z = f2bf(v.z); o.w = f2bf(v.w);
        *(ushort4*)(x_bf + i) = o;
        return;
    }
    const int tx = tid & 31, ty = tid >> 5;     // 32 x 8
    const float* in; unsigned short* out; int R, C, b, bx, by;
    if (blk < 7168) {                       // qkv transposes (3072 blocks)
        int lb = blk - 4096;
        bx = lb & 1; lb >>= 1;
        by = lb & 31;
        const int z = lb >> 5;              // 0..47
        const int which = z >> 4; b = z & 15;
        in  = (which == 0) ? Wq : (which == 1) ? Wk : Wv;
        out = (which == 0) ? WqkT : (which == 1) ? (WqkT + 1024*1024) : WvT;
        R = 1024; C = 64;
    } else if (blk < 8192) {                // Wo (1024 blocks, grid 32x32)
        const int lb = blk - 7168;
        bx = lb & 31; by = lb >> 5;
        in = Wo; out = WoT; R = 1024; C = 1024; b = 0;
    } else if (blk < 12288) {               // W1 (4096 blocks, grid 128x32)
        const int lb = blk - 8192;
        bx = lb & 127; by = lb >> 7;
        in = W1; out = W1T; R = 1024; C = 4096; b = 0;
    } else {                                // W2 (4096 blocks, grid 32x128)
        const int lb = blk - 12288;
        bx = lb & 31; by = lb >> 5;
        in = W2; out = W2T; R = 4096; C = 1024; b = 0;
    }
    const int c0 = bx * 32, r0 = by * 32;
    const float* inb = in + (size_t)b * R * C;
    unsigned short* outb = out + (size_t)b * R * C;
    #pragma unroll
    for (int i = 0; i < 4; ++i)
        tile[ty + i*8][tx] = inb[(size_t)(r0 + ty + i*8) * C + c0 + tx];
    __syncthreads();
    #pragma unroll
    for (int i = 0; i < 4; ++i)
        outb[(size_t)(c0 + ty + i*8) * R + r0 + tx] = f2bf(tile[tx][ty + i*8]);
}

// ---------------- GEMM 128x128 tile, 3-buf depth-2, 1 barrier/step -----------
// EPI 0: Cb = bf16(AB)
// EPI 4: Cb = bf16(AB * (col<1024 ? 0.125*log2e : 1))   (QK, Q in exp2 domain)
// EPI 5: split-K partial: Cb[z] = bf16(AB over K-chunk z) (MLP2; grid.z = 2)
template<int EPI>
__global__ __launch_bounds__(256) void gemm_bt(
    const unsigned short* __restrict__ A,
    const unsigned short* __restrict__ BT,
    const float* __restrict__ bias,
    const float* __restrict__ resid,
    float* __restrict__ Cf,
    unsigned short* __restrict__ Cb,
    int M, int N, int K, int klen)
{
    __shared__ unsigned short As[3][128 * 32];
    __shared__ unsigned short Bs[3][128 * 32];
    const int tid = threadIdx.x;
    const int w  = tid >> 6, l = tid & 63;
    const int wr = w >> 1,  wc = w & 1;
    const int lg = l >> 4,  ll = l & 15;
    int bx = blockIdx.x, by = blockIdx.y;
    xcd_remap(bx, by);
    const int m0 = by * 128, n0 = bx * 128;
    const int koff = (EPI == 5) ? (int)blockIdx.z * klen : 0;

    const int srow = w * 16 + (l >> 2);                     // staging row (i adds 64)
    const int scol = (((l & 3) ^ ((l >> 2) & 3))) * 8;      // swizzled source granule

    f32x4 acc[4][4] = {};

    auto stage = [&](int buf, int k0) {
        #pragma unroll
        for (int i = 0; i < 2; ++i) {
            load_lds16(A  + (size_t)(m0 + srow + i*64) * K + koff + k0 + scol,
                       (char*)As[buf] + i*4096 + w*1024);
            load_lds16(BT + (size_t)(n0 + srow + i*64) * K + koff + k0 + scol,
                       (char*)Bs[buf] + i*4096 + w*1024);
        }
    };

    const int nsteps = ((EPI == 5) ? klen : K) >> 5;
    stage(0, 0); stage(1, 32);
    int buf = 0;
    for (int s = 0; s < nsteps; ++s) {
        if (s + 1 < nsteps) asm volatile("s_waitcnt vmcnt(4)" ::: "memory");
        else                asm volatile("s_waitcnt vmcnt(0)" ::: "memory");
        __builtin_amdgcn_s_barrier();
        s16x8 a[4], b[4];
        #pragma unroll
        for (int m = 0; m < 4; ++m) {
            const int row = wr*64 + m*16 + ll;
            a[m] = *(const s16x8*)&As[buf][row * 32 + ((lg ^ (ll & 3)) * 8)];
        }
        #pragma unroll
        for (int n = 0; n < 4; ++n) {
            const int row = wc*64 + n*16 + ll;
            b[n] = *(const s16x8*)&Bs[buf][row * 32 + ((lg ^ (ll & 3)) * 8)];
        }
        int bnext = buf + 2; if (bnext >= 3) bnext -= 3;
        if (s + 2 < nsteps) stage(bnext, (s + 2) << 5);
        __builtin_amdgcn_s_setprio(1);
        #pragma unroll
        for (int m = 0; m < 4; ++m)
            #pragma unroll
            for (int n = 0; n < 4; ++n)
                acc[m][n] = __builtin_amdgcn_mfma_f32_16x16x32_bf16(a[m], b[n], acc[m][n], 0, 0, 0);
        __builtin_amdgcn_s_setprio(0);
        buf = (buf == 2) ? 0 : buf + 1;
    }

    unsigned short* Cbz = (EPI == 5) ? (Cb + (size_t)blockIdx.z * M * N) : Cb;
    #pragma unroll
    for (int m = 0; m < 4; ++m) {
        #pragma unroll
        for (int n = 0; n < 4; ++n) {
            const int col = n0 + wc*64 + n*16 + ll;
            #pragma unroll
            for (int r = 0; r < 4; ++r) {
                const int row = m0 + wr*64 + m*16 + lg*4 + r;
                float v = acc[m][n][r];
                if constexpr (EPI == 4) v *= (col < 1024) ? 0.1803368801f : 1.0f;
                Cbz[(size_t)row * N + col] = f2bf(v);
            }
        }
    }
}

// ---------------- MLP1: 256x256 tile, 8 waves, 3-buf/1-barrier ---------------
// (r16-verified version)
__global__ __launch_bounds__(512) void gemm_mlp1_k(
    const unsigned short* __restrict__ A,
    const unsigned short* __restrict__ BT,
    const float* __restrict__ bias,
    unsigned short* __restrict__ Cb,
    int M, int N, int K)
{
    __shared__ unsigned short As[3][256 * 32];
    __shared__ unsigned short Bs[3][256 * 32];
    const int tid = threadIdx.x;
    const int w  = tid >> 6, l = tid & 63;      // w in [0,8)
    const int wr = w >> 2,  wc = w & 3;         // 2 x 4 wave grid
    const int lg = l >> 4,  ll = l & 15;
    int bx = blockIdx.x, by = blockIdx.y;
    xcd_remap(bx, by);
    const int m0 = by * 256, n0 = bx * 256;

    const int srow = w * 16 + (l >> 2);         // +i*128 for second half
    const int scol = (((l & 3) ^ ((l >> 2) & 3))) * 8;

    f32x4 acc[8][4] = {};

    auto stage = [&](int buf, int k0) {
        #pragma unroll
        for (int i = 0; i < 2; ++i) {
            load_lds16(A  + (size_t)(m0 + srow + i*128) * K + k0 + scol,
                       (char*)As[buf] + i*8192 + w*1024);
            load_lds16(BT + (size_t)(n0 + srow + i*128) * K + k0 + scol,
                       (char*)Bs[buf] + i*8192 + w*1024);
        }
    };

    const int nsteps = K >> 5;
    stage(0, 0); stage(1, 32);
    int buf = 0;
    for (int s = 0; s < nsteps; ++s) {
        if (s + 1 < nsteps) asm volatile("s_waitcnt vmcnt(4)" ::: "memory");
        else                asm volatile("s_waitcnt vmcnt(0)" ::: "memory");
        __builtin_amdgcn_s_barrier();
        s16x8 a[8], b[4];
        #pragma unroll
        for (int m = 0; m < 8; ++m) {
            const int row = wr*128 + m*16 + ll;         // 0..255
            a[m] = *(const s16x8*)&As[buf][row * 32 + ((lg ^ (ll & 3)) * 8)];
        }
        #pragma unroll
        for (int n = 0; n < 4; ++n) {
            const int row = wc*64 + n*16 + ll;          // 0..255
            b[n] = *(const s16x8*)&Bs[buf][row * 32 + ((lg ^ (ll & 3)) * 8)];
        }
        int bnext = buf + 2; if (bnext >= 3) bnext -= 3;
        if (s + 2 < nsteps) stage(bnext, (s + 2) << 5);
        __builtin_amdgcn_s_setprio(1);
        #pragma unroll
        for (int m = 0; m < 8; ++m)
            #pragma unroll
            for (int n = 0; n < 4; ++n)
                acc[m][n] = __builtin_amdgcn_mfma_f32_16x16x32_bf16(a[m], b[n], acc[m][n], 0, 0, 0);
        __builtin_amdgcn_s_setprio(0);
        buf = (buf == 2) ? 0 : buf + 1;
    }

    #pragma unroll
    for (int m = 0; m < 8; ++m) {
        #pragma unroll
        for (int n = 0; n < 4; ++n) {
            const int col = n0 + wc*64 + n*16 + ll;
            #pragma unroll
            for (int r = 0; r < 4; ++r) {
                const int row = m0 + wr*128 + m*16 + lg*4 + r;
                Cb[(size_t)row * N + col] = f2bf(gelu_tanh(acc[m][n][r] + bias[col]));
            }
        }
    }
}

// ---------------- GEMM 128x64 tile, depth-4 pipeline --------------------------
// EPI 0: Cb = bf16(AB)                        (Vt)
// EPI 1: v = AB+bias+resid; Cf=v; Cb=bf16(v)  (Wo)
template<int EPI>
__global__ __launch_bounds__(256) void gemm_bt64(
    const unsigned short* __restrict__ A,
    const unsigned short* __restrict__ BT,
    const float* __restrict__ bias,
    const float* __restrict__ resid,
    float* __restrict__ Cf,
    unsigned short* __restrict__ Cb,
    int M, int N, int K)
{
    __shared__ unsigned short As[4][128 * 32];
    __shared__ unsigned short Bs[4][64 * 32];
    const int tid = threadIdx.x;
    const int w  = tid >> 6, l = tid & 63;
    const int lg = l >> 4,  ll = l & 15;
    int bx = blockIdx.x, by = blockIdx.y;
    xcd_remap(bx, by);
    const int m0 = by * 128, n0 = bx * 64;

    const int srowA = w * 16 + (l >> 2);
    const int scolA = (((l & 3) ^ ((l >> 2) & 3))) * 8;
    const int srowB = tid >> 2;
    const int scolB = (((tid & 3) ^ ((tid >> 2) & 3))) * 8;

    f32x4 acc[2][4] = {};

    auto stage = [&](int buf, int k0) {
        #pragma unroll
        for (int i = 0; i < 2; ++i)
            load_lds16(A + (size_t)(m0 + srowA + i*64) * K + k0 + scolA,
                       (char*)As[buf] + i*4096 + w*1024);
        load_lds16(BT + (size_t)(n0 + srowB) * K + k0 + scolB,
                   (char*)Bs[buf] + w*1024);
    };

    const int nsteps = K >> 5;                 // >= 32 for all our K
    stage(0, 0); stage(1, 32); stage(2, 64);
    int buf = 0;
    for (int s = 0; s < nsteps; ++s) {
        const int rem = nsteps - 1 - s;
        if (rem >= 2)      asm volatile("s_waitcnt vmcnt(6)" ::: "memory");
        else if (rem == 1) asm volatile("s_waitcnt vmcnt(3)" ::: "memory");
        else               asm volatile("s_waitcnt vmcnt(0)" ::: "memory");
        __builtin_amdgcn_s_barrier();
        s16x8 a[2], b[4];
        #pragma unroll
        for (int m = 0; m < 2; ++m) {
            const int row = w*32 + m*16 + ll;
            a[m] = *(const s16x8*)&As[buf][row * 32 + ((lg ^ (ll & 3)) * 8)];
        }
        #pragma unroll
        for (int n = 0; n < 4; ++n) {
            const int row = n*16 + ll;
            b[n] = *(const s16x8*)&Bs[buf][row * 32 + ((lg ^ (ll & 3)) * 8)];
        }
        int bnext = buf + 3; if (bnext >= 4) bnext -= 4;
        if (s + 3 < nsteps) stage(bnext, (s + 3) << 5);
        __builtin_amdgcn_s_setprio(1);
        #pragma unroll
        for (int m = 0; m < 2; ++m)
            #pragma unroll
            for (int n = 0; n < 4; ++n)
                acc[m][n] = __builtin_amdgcn_mfma_f32_16x16x32_bf16(a[m], b[n], acc[m][n], 0, 0, 0);
        __builtin_amdgcn_s_setprio(0);
        buf = (buf + 1) & 3;
    }

    #pragma unroll
    for (int m = 0; m < 2; ++m) {
        #pragma unroll
        for (int n = 0; n < 4; ++n) {
            const int col = n0 + n*16 + ll;
            #pragma unroll
            for (int r = 0; r < 4; ++r) {
                const int row = m0 + w*32 + m*16 + lg*4 + r;
                float v = acc[m][n][r];
                if constexpr (EPI == 1) v += bias[col] + resid[(size_t)row * N + col];
                Cb[(size_t)row * N + col] = f2bf(v);
                if constexpr (EPI == 1)
                    Cf[(size_t)row * N + col] = v;
            }
        }
    }
}

// MLP2 combine: out = p0 + p1 + bias + resid   (f32 final output)
__global__ __launch_bounds__(256) void mlp2_combine_k(
    const unsigned short* __restrict__ P,   // [2][4096][1024] bf16 partials
    const float* __restrict__ bias,
    const float* __restrict__ resid,
    float* __restrict__ out)
{
    const int idx = (blockIdx.x * 256 + threadIdx.x) * 4;
    const int col = idx & 1023;
    ushort4 a = *(const ushort4*)(P + idx);
    ushort4 b = *(const ushort4*)(P + 4194304 + idx);
    float4 rs = *(const float4*)(resid + idx);
    float4 o;
    o.x = bf2f(a.x) + bf2f(b.x) + bias[col]     + rs.x;
    o.y = bf2f(a.y) + bf2f(b.y) + bias[col + 1] + rs.y;
    o.z = bf2f(a.z) + bf2f(b.z) + bias[col + 2] + rs.z;
    o.w = bf2f(a.w) + bf2f(b.w) + bias[col + 3] + rs.w;
    *(float4*)(out + idx) = o;
}

// ---------------- flash attention: padded LDS (LDK=72), reg-staged K/V --------
// (r17-verified version: 51.8 us, VGPR 84, NO launch_bounds occupancy pin —
// r18's (512,4) pin forced VGPR<=64 and spilled 478MB/dispatch to scratch.)
__global__ __launch_bounds__(512) void attn_k(
    const unsigned short* __restrict__ Rq,  // K_mat rows (output rows), stride 2048
    const unsigned short* __restrict__ Ck,  // Q_mat (staged tiles, exp2-prescaled)
    const unsigned short* __restrict__ Vt,  // V^T [1024][4096]
    unsigned short* __restrict__ Ppart,     // [2][4096][1024] bf16 partial o
    float* __restrict__ Lpart)              // [2][4096][16]  f32 partial lsum
{
    constexpr int LDK = 72;                 // padded row, 144B
    __shared__ unsigned short Ks[2][2][64 * LDK];
    __shared__ unsigned short Vs[2][2][64 * LDK];

    const int bx = blockIdx.x;
    const int h  = bx & 15;
    const int j  = (bx >> 4) & 1;           // kv half
    const int sb = 15 - (bx >> 5);          // 256-row s-blocks, heavy first
    const int half = 2*sb + 2;
    const int t0 = j ? half : 0;
    const int npairs = sb + 1;              // tiles per half / 2

    const int tid = threadIdx.x;
    const int w = tid >> 6, l = tid & 63;   // w in [0,8)
    const int lg = l >> 4, ll = l & 15;

    // staging: each wave stages rows w*8..w*8+7 of K tile and of V^T tile
    const int srow = w*8 + (l >> 3);
    const int sgE  = (l & 7) * 8;           // element offset within row
    const size_t kGb = (size_t)srow * 2048 + h*64 + sgE;
    const size_t vGb = (size_t)(h*64 + srow) * 4096 + sgE;
    const int ldsW = srow * LDK + sgE;      // element offset (16B-aligned)

    // QK LDS read byte-offsets (plain layout, padded stride)
    int qkoff[4][2];
    #pragma unroll
    for (int jj = 0; jj < 4; ++jj) {
        const int row = jj*16 + ll;
        qkoff[jj][0] = row*144 + lg*16;
        qkoff[jj][1] = row*144 + (4 + lg)*16;
    }
    // PV LDS read byte-offsets
    int pvoff[4][2][2];
    #pragma unroll
    for (int n = 0; n < 4; ++n) {
        const int row = n*16 + ll;
        #pragma unroll
        for (int c = 0; c < 2; ++c) {
            const int gl = c*4     + (lg >> 1);
            const int gh = c*4 + 2 + (lg >> 1);
            pvoff[n][c][0] = row*144 + gl*16 + (lg & 1)*8;
            pvoff[n][c][1] = row*144 + gh*16 + (lg & 1)*8;
        }
    }

    s16x8 kr[2], vr[2];                     // staged pair (K,V x 2 tiles)
    auto loadPair = [&](int p) {
        const int t = t0 + 2*p;
        kr[0] = *(const s16x8*)&Ck[(size_t)t * 131072 + kGb];
        vr[0] = *(const s16x8*)&Vt[(size_t)t * 64 + vGb];
        kr[1] = *(const s16x8*)&Ck[(size_t)(t + 1) * 131072 + kGb];
        vr[1] = *(const s16x8*)&Vt[(size_t)(t + 1) * 64 + vGb];
    };
    auto writePair = [&](int set) {
        *(s16x8*)&Ks[set][0][ldsW] = kr[0];
        *(s16x8*)&Vs[set][0][ldsW] = vr[0];
        *(s16x8*)&Ks[set][1][ldsW] = kr[1];
        *(s16x8*)&Vs[set][1][ldsW] = vr[1];
    };

    // two rowsets of 16 output rows each (32 rows per wave)
    const int row0 = sb*256 + w*32;
    const int qgA  = row0 + ll;             // rowset 0: lane's output row
    const int qgB  = row0 + 16 + ll;        // rowset 1
    const size_t rbA = (size_t)qgA * 2048 + h*64;
    const size_t rbB = (size_t)qgB * 2048 + h*64;
    const s16x8 rA0 = *(const s16x8*)&Rq[rbA + lg*8];
    const s16x8 rA1 = *(const s16x8*)&Rq[rbA + 32 + lg*8];
    const s16x8 rB0 = *(const s16x8*)&Rq[rbB + lg*8];
    const s16x8 rB1 = *(const s16x8*)&Rq[rbB + 32 + lg*8];

    const short onebf = (short)0x3F80;      // bf16 1.0
    const s16x8 ones = {onebf, onebf, onebf, onebf, onebf, onebf, onebf, onebf};

    f32x4 o[2][4] = {};
    f32x4 o4[2] = {};                       // rowsum(P) accumulators

    // one kv tile (r17-verified body)
    auto tileCompute = [&](int t, const unsigned short* kb_, const unsigned short* vb_) {
        const char* kb = (const char*)kb_;
        const char* vb = (const char*)vb_;
        const bool live = (t*64 <= row0 + 31);
        const bool anyMask = (t*64 + 63 > row0);
        if (!live) return;

        f32x4 st[2][4];
        __builtin_amdgcn_s_setprio(1);
        #pragma unroll
        for (int jj = 0; jj < 4; ++jj) {
            s16x8 k0 = *(const s16x8*)(kb + qkoff[jj][0]);
            s16x8 k1 = *(const s16x8*)(kb + qkoff[jj][1]);
            f32x4 z = {0.f, 0.f, 0.f, 0.f};
            f32x4 ta = __builtin_amdgcn_mfma_f32_16x16x32_bf16(k0, rA0, z, 0, 0, 0);
            st[0][jj] = __builtin_amdgcn_mfma_f32_16x16x32_bf16(k1, rA1, ta, 0, 0, 0);
            f32x4 tb = __builtin_amdgcn_mfma_f32_16x16x32_bf16(k0, rB0, z, 0, 0, 0);
            st[1][jj] = __builtin_amdgcn_mfma_f32_16x16x32_bf16(k1, rB1, tb, 0, 0, 0);
        }
        __builtin_amdgcn_s_setprio(0);

        float p[2][4][4];
        if (anyMask) {
            #pragma unroll
            for (int jj = 0; jj < 4; ++jj)
                #pragma unroll
                for (int r = 0; r < 4; ++r) {
                    const int jg = t*64 + jj*16 + lg*4 + r;
                    p[0][jj][r] = exp2_fast((jg > qgA) ? -3e38f : st[0][jj][r]);
                    p[1][jj][r] = exp2_fast((jg > qgB) ? -3e38f : st[1][jj][r]);
                }
        } else {
            #pragma unroll
            for (int rs = 0; rs < 2; ++rs)
                #pragma unroll
                for (int jj = 0; jj < 4; ++jj)
                    #pragma unroll
                    for (int r = 0; r < 4; ++r)
                        p[rs][jj][r] = exp2_fast(st[rs][jj][r]);
        }

        s16x8 apv[2][2];
        #pragma unroll
        for (int rs = 0; rs < 2; ++rs)
            #pragma unroll
            for (int c = 0; c < 2; ++c) {
                union { unsigned u[4]; s16x8 v; } pk;
                pk.u[0] = cvt_pk_bf16(p[rs][2*c][0],   p[rs][2*c][1]);
                pk.u[1] = cvt_pk_bf16(p[rs][2*c][2],   p[rs][2*c][3]);
                pk.u[2] = cvt_pk_bf16(p[rs][2*c+1][0], p[rs][2*c+1][1]);
                pk.u[3] = cvt_pk_bf16(p[rs][2*c+1][2], p[rs][2*c+1][3]);
                apv[rs][c] = pk.v;
            }
        __builtin_amdgcn_s_setprio(1);
        #pragma unroll
        for (int rs = 0; rs < 2; ++rs) {
            o4[rs] = __builtin_amdgcn_mfma_f32_16x16x32_bf16(apv[rs][0], ones, o4[rs], 0, 0, 0);
            o4[rs] = __builtin_amdgcn_mfma_f32_16x16x32_bf16(apv[rs][1], ones, o4[rs], 0, 0, 0);
        }
        #pragma unroll
        for (int n = 0; n < 4; ++n) {
            #pragma unroll
            for (int c = 0; c < 2; ++c) {
                s16x4 lo = *(const s16x4*)(vb + pvoff[n][c][0]);
                s16x4 hi = *(const s16x4*)(vb + pvoff[n][c][1]);
                union { s16x4 h2[2]; s16x8 v; } u;
                u.h2[0] = lo; u.h2[1] = hi;
                o[0][n] = __builtin_amdgcn_mfma_f32_16x16x32_bf16(apv[0][c], u.v, o[0][n], 0, 0, 0);
                o[1][n] = __builtin_amdgcn_mfma_f32_16x16x32_bf16(apv[1][c], u.v, o[1][n], 0, 0, 0);
            }
        }
        __builtin_amdgcn_s_setprio(0);
    };

    loadPair(0);
    for (int p = 0; p < npairs; ++p) {
        const int set = p & 1;
        writePair(set);                     // compiler inserts vmcnt waits on kr/vr
        __syncthreads();                    // lgkm drain + barrier
        if (p + 1 < npairs) loadPair(p + 1);
        const int t = t0 + 2*p;
        tileCompute(t,     Ks[set][0], Vs[set][0]);
        tileCompute(t + 1, Ks[set][1], Vs[set][1]);
    }

    // epilogue: write UNNORMALIZED partials (additive across halves)
    unsigned short* Pout = Ppart + (size_t)j * 4194304;     // 4096*1024
    float* Lout = Lpart + (size_t)j * 65536;                // 4096*16
    #pragma unroll
    for (int rs = 0; rs < 2; ++rs)
        #pragma unroll
        for (int r = 0; r < 4; ++r) {
            const int row = row0 + rs*16 + lg*4 + r;
            const size_t orow = (size_t)row * 1024 + h * 64;
            #pragma unroll
            for (int n = 0; n < 4; ++n)
                Pout[orow + n*16 + ll] = f2bf(o[rs][n][r]);
            if (ll == 0) Lout[row * 16 + h] = o4[rs][r];
        }
}

// combine: attn[row][col] = (P0 + P1) / (L0 + L1)
__global__ __launch_bounds__(256) void attn_combine_k(
    const unsigned short* __restrict__ P,   // [2][4096][1024] bf16
    const float* __restrict__ L,            // [2][4096][16]  f32
    unsigned short* __restrict__ Out)       // [4096][1024]   bf16
{
    const int idx = (blockIdx.x * 256 + threadIdx.x) * 4;
    const int row = idx >> 10, h = (idx & 1023) >> 6;
    const float inv = 1.f / (L[row*16 + h] + L[65536 + row*16 + h]);
    ushort4 a = *(const ushort4*)(P + idx);
    ushort4 b = *(const ushort4*)(P + 4194304 + idx);
    ushort4 o;
    o.x = f2bf((bf2f(a.x) + bf2f(b.x)) * inv);
    o.y = f2bf((bf2f(a.y) + bf2f(b.y)) * inv);
    o.z = f2bf((bf2f(a.z) + bf2f(b.z)) * inv);
    o.w = f2bf((bf2f(a.w) + bf2f(b.w)) * inv);
    *(ushort4*)(Out + idx) = o;
}

// ---------------- launch ----------------

extern "C" void kernel_launch(void* const* d_in, const int* in_sizes, int n_in,
                              void* d_out, int out_size, void* d_ws, size_t ws_size,
                              hipStream_t stream) {
    const float* x  = (const float*)d_in[0];
    const float* Wk = (const float*)d_in[1];
    const float* Wq = (const float*)d_in[2];
    const float* Wv = (const float*)d_in[3];
    const float* Wo = (const float*)d_in[4];
    const float* bo = (const float*)d_in[5];
    const float* W1 = (const float*)d_in[6];
    const float* b1 = (const float*)d_in[7];
    const float* W2 = (const float*)d_in[8];
    const float* b2 = (const float*)d_in[9];
    float* out = (float*)d_out;

    char* ws = (char*)d_ws;
    unsigned short* x_bf  = (unsigned short*)(ws);                // 0..8 MiB
    unsigned short* WqkT  = (unsigned short*)(ws + (8u  << 20));  // 8..12 (2048x1024)
    unsigned short* WvT   = (unsigned short*)(ws + (12u << 20));  // 12..14 (1024x1024)
    unsigned short* WoT   = (unsigned short*)(ws + (14u << 20));  // 14..16
    unsigned short* W1T   = (unsigned short*)(ws + (16u << 20));  // 16..24
    unsigned short* W2T   = (unsigned short*)(ws + (24u << 20));  // 24..32
    unsigned short* QKm   = (unsigned short*)(ws + (32u << 20));  // 32..48 (4096x2048)
    unsigned short* attn  = (unsigned short*)(ws + (48u << 20));  // 48..56
    unsigned short* Vt    = (unsigned short*)(ws + (56u << 20));  // 56..64 (1024x4096)
    float*          yf    = (float*)(ws + (64u << 20));           // 64..80 f32
    // dead-region reuse:
    float*          Lpart = (float*)ws;                           // attn lsum partials (x_bf region)
    unsigned short* Ppart = (unsigned short*)(ws + (64u << 20));  // attn o partials (yf region)
    unsigned short* Pmlp  = (unsigned short*)(ws);                // MLP2 partials, 0..16 MiB (dead by then)
    unsigned short* y_bf  = x_bf;                                 // x_bf dead after V-GEMM
    unsigned short* h_bf  = QKm;   // 32..64 MiB (QKm+attn+Vt dead after Wo GEMM)

    // fused pre-pass: convert + all transposes in ONE dispatch
    prep_k<<<16384, 256, 0, stream>>>(x, Wq, Wk, Wv, Wo, W1, W2,
                                      x_bf, WqkT, WvT, WoT, W1T, W2T);

    // fused Q|K projection (128^2 tiles), Q pre-scaled by 0.125*log2e (exp2 domain)
    gemm_bt<4><<<dim3(16, 32), 256, 0, stream>>>(x_bf, WqkT, nullptr, nullptr, nullptr,
                                                 QKm, 4096, 2048, 1024, 1024);
    // V^T directly: Vt[e][s] = sum_d WvT[e][d] * x[s][d]
    gemm_bt64<0><<<dim3(64, 8), 256, 0, stream>>>(WvT, x_bf, nullptr, nullptr, nullptr,
                                                  Vt, 1024, 4096, 1024);

    attn_k<<<512, 512, 0, stream>>>(QKm + 1024 /*K*/, QKm /*Q*/, Vt, Ppart, Lpart);
    attn_combine_k<<<4096, 256, 0, stream>>>(Ppart, Lpart, attn);

    gemm_bt64<1><<<dim3(16, 32), 256, 0, stream>>>(attn, WoT, bo, x, yf, y_bf,
                                                   4096, 1024, 1024);
    // MLP1: 256x256 tile, 8 waves, 3-buf -> 256 WGs = exactly 1/CU
    gemm_mlp1_k<<<dim3(16, 16), 512, 0, stream>>>(y_bf, W1T, b1, h_bf, 4096, 4096, 1024);
    // MLP2: 128^2 tile + split-K x2 (grid.z = 2, K=2048 each), bf16 partials + combine
    gemm_bt<5><<<dim3(8, 32, 2), 256, 0, stream>>>(h_bf, W2T, nullptr, nullptr, nullptr,
                                                   Pmlp, 4096, 1024, 4096, 2048);
    mlp2_combine_k<<<4096, 256, 0, stream>>>(Pmlp, b2, yf, out);
}